// Round 10
// baseline (166.824 us; speedup 1.0000x reference)
//
#include <hip/hip_runtime.h>
#include <math.h>

// STRNN: B=16, S=128, D=64, K=64, H=128, NSLOT+1=97 slots.
//
// Pipeline:
//  k_hist1    : per-block LDS histograms of t-slot / d-slot / per-(b,i) counts
//  k_scan_all : exclusive scans -> per-(bin,block) bases + OFF_T/OFF_D/OFF_B
//  k_scatter  : one pass; LDS cursors; emits t-sorted entries, d-sorted refs, Y slots
//  k_phaseA   : per t-bucket GEMM  xt = x[b,j] @ Tw[t]  (VALU f32) -> XT[tpos][64]
//  k_phaseB   : per d-bucket GEMM  y = xt @ Dw[d]  via MFMA f16 (f32 accum) -> Y
//  k_reduce   : XC[b,i,:] = sum of its contiguous Y rows
//  k_recur    : h = sigmoid(XC[b,i] + h@Wh); SINGLE WAVE per batch, no barrier,
//               2 cols/lane, Wh in VGPRs as half2, XC prefetched 4 steps deep.
//
// ws requirement: ~104.3 MB for the atomic-free path (guarded; fallback = atomicAdd XC).

#define B_ 16
#define S_ 128
#define D_ 64
#define K_ 64
#define H_ 128
#define NS 97
#define MAXE 132096  // B * S*(S+1)/2  (upper bound on valid triples)

// u32/f32-index offsets into ws
#define XC_OFF 0                  // f32 [2048][128]
#define BH_T   262144             // u32 [97][256]  per-(bin,block) hist -> bases
#define BH_D   (BH_T + 24832)     // u32 [97][256]
#define CNT_T  (BH_D + 24832)     // u32 [97]
#define CNT_D  (CNT_T + 97)       // u32 [97]
#define CNT_B  (CNT_D + 97)       // u32 [2048]
#define OFF_T  (CNT_B + 2048)     // u32 [98] (last = total)
#define OFF_D  (OFF_T + 98)       // u32 [98]
#define OFF_B  (OFF_D + 98)       // u32 [2049]
#define ENT_T  316296             // u32 [MAXE] packed: b|i<<4|j<<11|t<<18|d<<25 (16B-aligned)
#define ENT_DX (ENT_T + MAXE)     // u32 [MAXE] xt-row index (t-sorted pos)
#define ENT_DP (ENT_DX + MAXE)    // u32 [MAXE] Y-row (dst-sorted pos) [or dst in fallback]
#define XT_OFF (ENT_DP + MAXE)    // f32 [MAXE][64]
#define Y_OFF  (XT_OFF + MAXE * 64)            // f32 [MAXE][128]
#define NEED_BYTES ((size_t)(Y_OFF + (size_t)MAXE * 128) * 4)

typedef _Float16 h2_t __attribute__((ext_vector_type(2)));
typedef _Float16 f16x8 __attribute__((ext_vector_type(8)));
typedef float f32x4 __attribute__((ext_vector_type(4)));

#if __has_builtin(__builtin_amdgcn_fdot2)
#define FDOT2(a, b, c) __builtin_amdgcn_fdot2((a), (b), (c), false)
#else
#define FDOT2(a, b, c) ((c) + (float)(a)[0] * (float)(b)[0] + (float)(a)[1] * (float)(b)[1])
#endif

// ---- binning: 256 blocks x 1024 elements (8 full (b,i) rows per block) ----

__global__ __launch_bounds__(256) void k_hist1(const int* __restrict__ tc,
                                               const int* __restrict__ dc,
                                               const int* __restrict__ mk,
                                               unsigned* wsi) {
    __shared__ unsigned ht[NS], hd[NS], hb[8];
    int tid = threadIdx.x, blk = blockIdx.x;
    if (tid < NS) { ht[tid] = 0; hd[tid] = 0; }
    if (tid < 8) hb[tid] = 0;
    __syncthreads();
    int base = blk * 1024;
    #pragma unroll
    for (int u = 0; u < 4; u++) {
        int idx = base + tid + u * 256;
        int i = (idx >> 7) & 127, j = idx & 127;
        if (j <= i && mk[idx] != 0) {
            atomicAdd(&ht[tc[idx]], 1u);
            atomicAdd(&hd[dc[idx]], 1u);
            atomicAdd(&hb[(idx >> 7) & 7], 1u);
        }
    }
    __syncthreads();
    if (tid < NS) {
        wsi[BH_T + tid * 256 + blk] = ht[tid];
        wsi[BH_D + tid * 256 + blk] = hd[tid];
    }
    if (tid < 8) wsi[CNT_B + blk * 8 + tid] = hb[tid];
}

template <int CH>
__device__ unsigned scan_region(unsigned* in, unsigned* out, int L, unsigned* s) {
    int tid = threadIdx.x;
    unsigned loc[CH], sum = 0;
    #pragma unroll
    for (int k = 0; k < CH; k++) {
        int idx = tid * CH + k;
        loc[k] = (idx < L) ? in[idx] : 0u;
        sum += loc[k];
    }
    s[tid] = sum;
    __syncthreads();
    for (int o = 1; o < 1024; o <<= 1) {
        unsigned a = (tid >= o) ? s[tid - o] : 0u;
        __syncthreads();
        s[tid] += a;
        __syncthreads();
    }
    unsigned total = s[1023];
    unsigned run = s[tid] - sum;
    __syncthreads();
    #pragma unroll
    for (int k = 0; k < CH; k++) {
        int idx = tid * CH + k;
        if (idx < L) { out[idx] = run; run += loc[k]; }
    }
    __syncthreads();
    return total;
}

__global__ __launch_bounds__(1024) void k_scan_all(unsigned* wsi) {
    __shared__ unsigned s[1024];
    int tid = threadIdx.x;

    unsigned totT = scan_region<25>(wsi + BH_T, wsi + BH_T, NS * 256, s);
    if (tid < NS) {
        unsigned b0 = wsi[BH_T + tid * 256];
        unsigned b1 = (tid < NS - 1) ? wsi[BH_T + (tid + 1) * 256] : totT;
        wsi[OFF_T + tid] = b0;
        wsi[CNT_T + tid] = b1 - b0;
    }
    if (tid == 0) wsi[OFF_T + NS] = totT;
    __syncthreads();

    unsigned totD = scan_region<25>(wsi + BH_D, wsi + BH_D, NS * 256, s);
    if (tid < NS) {
        unsigned b0 = wsi[BH_D + tid * 256];
        unsigned b1 = (tid < NS - 1) ? wsi[BH_D + (tid + 1) * 256] : totD;
        wsi[OFF_D + tid] = b0;
        wsi[CNT_D + tid] = b1 - b0;
    }
    if (tid == 0) wsi[OFF_D + NS] = totD;
    __syncthreads();

    unsigned totB = scan_region<2>(wsi + CNT_B, wsi + OFF_B, 2048, s);
    if (tid == 0) wsi[OFF_B + 2048] = totB;
}

__global__ __launch_bounds__(256) void k_scatter(const int* __restrict__ tc,
                                                 const int* __restrict__ dc,
                                                 const int* __restrict__ mk,
                                                 unsigned* wsi, int useY) {
    __shared__ unsigned ct[NS], cd[NS], cb[8];
    int tid = threadIdx.x, blk = blockIdx.x;
    if (tid < NS) {
        ct[tid] = wsi[BH_T + tid * 256 + blk];
        cd[tid] = wsi[BH_D + tid * 256 + blk];
    }
    if (tid < 8) cb[tid] = wsi[OFF_B + blk * 8 + tid];
    __syncthreads();
    int base = blk * 1024;
    #pragma unroll
    for (int u = 0; u < 4; u++) {
        int idx = base + tid + u * 256;
        int i = (idx >> 7) & 127, j = idx & 127, b = idx >> 14;
        if (j <= i && mk[idx] != 0) {
            unsigned t = (unsigned)tc[idx], d = (unsigned)dc[idx];
            unsigned tpos = atomicAdd(&ct[t], 1u);
            wsi[ENT_T + tpos] = (unsigned)b | ((unsigned)i << 4) | ((unsigned)j << 11)
                              | (t << 18) | (d << 25);
            unsigned dpos = atomicAdd(&cd[d], 1u);
            unsigned yp = useY ? atomicAdd(&cb[(idx >> 7) & 7], 1u) : (unsigned)(idx >> 7);
            wsi[ENT_DX + dpos] = tpos;
            wsi[ENT_DP + dpos] = yp;
        }
    }
}

// phase A: xt[entry][kk] = sum_dd x[b,j][dd] * Tw[t][dd][kk]  (VALU f32, unchanged)
__global__ __launch_bounds__(256) void k_phaseA(const float* __restrict__ x,
                                                const float* __restrict__ tw,
                                                unsigned* wsi, float* wsf) {
    int t = blockIdx.x, c = blockIdx.y;
    int rows = (int)wsi[CNT_T + t] - c * 128;
    if (rows <= 0) return;
    if (rows > 128) rows = 128;
    unsigned base = wsi[OFF_T + t] + c * 128;

    __shared__ float stw[4096];     // Tw[t] row-major [dd][kk]
    __shared__ float sx[8192];      // x rows, XOR-swizzled in 4-float units
    __shared__ unsigned ent[128];
    int tid = threadIdx.x;

    const float4* twg = (const float4*)(tw + t * 4096);
    float4* stw4 = (float4*)stw;
    #pragma unroll
    for (int q = 0; q < 4; q++) stw4[q * 256 + tid] = twg[q * 256 + tid];
    if (tid < 128) ent[tid] = (tid < rows) ? wsi[ENT_T + base + tid] : 0u;
    __syncthreads();

    int lane16 = tid & 15, rquot = tid >> 4;
    #pragma unroll
    for (int p = 0; p < 8; p++) {
        int r = p * 16 + rquot;
        float4 v = make_float4(0.f, 0.f, 0.f, 0.f);
        if (r < rows) {
            unsigned e = ent[r];
            int b = e & 15, j = (e >> 11) & 127;
            v = *(const float4*)(x + (b * S_ + j) * D_ + lane16 * 4);
        }
        int col4 = lane16 ^ (r & 15);
        float* dst = &sx[r * 64 + col4 * 4];
        dst[0] = v.x; dst[1] = v.y; dst[2] = v.z; dst[3] = v.w;
    }
    __syncthreads();

    int rgrp = tid & 15, cgrp = tid >> 4;   // 8 rows (rgrp+16i) x 4 cols (cgrp*4..)
    float4 acc[8];
    #pragma unroll
    for (int i = 0; i < 8; i++) acc[i] = make_float4(0.f, 0.f, 0.f, 0.f);
    #pragma unroll 4
    for (int dd = 0; dd < 64; dd++) {
        float4 w = stw4[dd * 16 + cgrp];
        int s_idx = (((dd >> 2) ^ rgrp) << 2) + (dd & 3);
        #pragma unroll
        for (int i = 0; i < 8; i++) {
            float a = sx[(rgrp + 16 * i) * 64 + s_idx];
            acc[i].x += a * w.x; acc[i].y += a * w.y;
            acc[i].z += a * w.z; acc[i].w += a * w.w;
        }
    }
    float* XT = wsf + XT_OFF;
    #pragma unroll
    for (int i = 0; i < 8; i++) {
        int r = rgrp + 16 * i;
        if (r < rows) *(float4*)(XT + (size_t)(base + r) * 64 + cgrp * 4) = acc[i];
    }
}

// phase B (MFMA f16): y[rows x 128] = XT-rows[rows x 64] @ Dw[d][64 x 128].
// A staged in LDS f16 with 8-half-chunk XOR swizzle (ds_read_b128 A-frags);
// B staged linear f16 (one-time 8x ds_read_u16 gather per B-frag, reused across rows).
// Wave w owns col strip [w*32, w*32+32): 8 row-tiles x 2 col-tiles x 2 K-steps.
__global__ __launch_bounds__(256) void k_phaseB(const float* __restrict__ dw,
                                                unsigned* wsi, float* wsf, int useY) {
    int d = blockIdx.x, c = blockIdx.y;
    int rows = (int)wsi[CNT_D + d] - c * 128;
    if (rows <= 0) return;
    if (rows > 128) rows = 128;
    unsigned base = wsi[OFF_D + d] + c * 128;

    __shared__ _Float16 sa[128 * 64];     // A: XT rows f16, chunk-swizzled (16 KB)
    __shared__ _Float16 sb[64 * 128];     // B: Dw f16 [k][h] linear (16 KB)
    __shared__ unsigned entx_s[128], entp_s[128];
    int tid = threadIdx.x;

    if (tid < 128) {
        entx_s[tid] = (tid < rows) ? wsi[ENT_DX + base + tid] : 0u;
        entp_s[tid] = (tid < rows) ? wsi[ENT_DP + base + tid] : 0u;
    }
    // stage Dw -> f16 linear (element order preserved)
    const float4* dwg = (const float4*)(dw + (size_t)d * 8192);
    #pragma unroll
    for (int q = 0; q < 8; q++) {
        float4 v = dwg[q * 256 + tid];
        union { _Float16 h[4]; double d64; } u;
        u.h[0] = (_Float16)v.x; u.h[1] = (_Float16)v.y;
        u.h[2] = (_Float16)v.z; u.h[3] = (_Float16)v.w;
        *(double*)&sb[(q * 256 + tid) * 4] = u.d64;
    }
    __syncthreads();   // entx_s ready for XT staging

    // stage XT rows -> f16, swizzled: thread = (row r = tid>>1, k-half hh = tid&1)
    {
        int r = tid >> 1, hh = tid & 1;
        const float* XT = wsf + XT_OFF;
        const float4* src = (const float4*)(XT + (size_t)entx_s[r] * 64 + hh * 32);
        #pragma unroll
        for (int mm = 0; mm < 4; mm++) {
            f16x8 hv = {0, 0, 0, 0, 0, 0, 0, 0};
            if (r < rows) {
                float4 v0 = src[mm * 2], v1 = src[mm * 2 + 1];
                hv[0] = (_Float16)v0.x; hv[1] = (_Float16)v0.y;
                hv[2] = (_Float16)v0.z; hv[3] = (_Float16)v0.w;
                hv[4] = (_Float16)v1.x; hv[5] = (_Float16)v1.y;
                hv[6] = (_Float16)v1.z; hv[7] = (_Float16)v1.w;
            }
            int chunk = hh * 4 + mm;                       // 8-half chunk 0..7
            *(f16x8*)&sa[r * 64 + (chunk ^ (r & 7)) * 8] = hv;
        }
    }
    __syncthreads();

    int w = tid >> 6, lane = tid & 63;
    int l15 = lane & 15, lg = lane >> 4;                   // lg = k-group
    // B fragments: B[k = ks*32 + lg*8 + e][col]
    f16x8 bf[2][2];
    #pragma unroll
    for (int n = 0; n < 2; n++) {
        int col = w * 32 + n * 16 + l15;
        #pragma unroll
        for (int ks = 0; ks < 2; ks++) {
            int kb = ks * 32 + lg * 8;
            f16x8 t;
            #pragma unroll
            for (int e = 0; e < 8; e++) t[e] = sb[(kb + e) * 128 + col];
            bf[n][ks] = t;
        }
    }
    f32x4 acc[8][2];
    f32x4 z = {0.f, 0.f, 0.f, 0.f};
    #pragma unroll
    for (int m = 0; m < 8; m++) { acc[m][0] = z; acc[m][1] = z; }

    #pragma unroll
    for (int m = 0; m < 8; m++) {
        int row = m * 16 + l15;
        f16x8 a0 = *(f16x8*)&sa[row * 64 + ((lg) ^ (row & 7)) * 8];        // ks=0
        f16x8 a1 = *(f16x8*)&sa[row * 64 + ((4 + lg) ^ (row & 7)) * 8];    // ks=1
        #pragma unroll
        for (int n = 0; n < 2; n++) {
            acc[m][n] = __builtin_amdgcn_mfma_f32_16x16x32_f16(a0, bf[n][0], acc[m][n], 0, 0, 0);
            acc[m][n] = __builtin_amdgcn_mfma_f32_16x16x32_f16(a1, bf[n][1], acc[m][n], 0, 0, 0);
        }
    }

    // epilogue: C layout col = lane&15, row = (lane>>4)*4 + reg  [m89-verified]
    if (useY) {
        float* Y = wsf + Y_OFF;
        #pragma unroll
        for (int m = 0; m < 8; m++) {
            #pragma unroll
            for (int reg = 0; reg < 4; reg++) {
                int row = m * 16 + lg * 4 + reg;
                if (row < rows) {
                    float* p = Y + (size_t)entp_s[row] * 128 + w * 32 + l15;
                    p[0]  = acc[m][0][reg];
                    p[16] = acc[m][1][reg];
                }
            }
        }
    } else {
        float* XC = wsf + XC_OFF;
        #pragma unroll
        for (int m = 0; m < 8; m++) {
            #pragma unroll
            for (int reg = 0; reg < 4; reg++) {
                int row = m * 16 + lg * 4 + reg;
                if (row < rows) {
                    float* p = XC + (size_t)entp_s[row] * 128 + w * 32 + l15;
                    atomicAdd(p + 0,  acc[m][0][reg]);
                    atomicAdd(p + 16, acc[m][1][reg]);
                }
            }
        }
    }
}

// XC[b,i,:] = sum of this (b,i)'s contiguous Y rows
__global__ __launch_bounds__(128) void k_reduce(unsigned* wsi, float* wsf) {
    int bi = blockIdx.x, tid = threadIdx.x;
    unsigned n = wsi[CNT_B + bi], off = wsi[OFF_B + bi];
    const float* Yp = wsf + Y_OFF + (size_t)off * 128 + tid;
    float a0 = 0.f, a1 = 0.f, a2 = 0.f, a3 = 0.f;
    unsigned e = 0;
    for (; e + 4 <= n; e += 4) {
        a0 += Yp[(size_t)e * 128];
        a1 += Yp[(size_t)(e + 1) * 128];
        a2 += Yp[(size_t)(e + 2) * 128];
        a3 += Yp[(size_t)(e + 3) * 128];
    }
    for (; e < n; e++) a0 += Yp[(size_t)e * 128];
    wsf[XC_OFF + (size_t)bi * 128 + tid] = (a0 + a1) + (a2 + a3);
}

// recurrence: h_new = sigmoid(XC[b,i] + h @ Wh); ONE WAVE per batch, NO barrier.
// Lane owns cols c0=2*lane, c0+1; Wh cols in VGPRs as half2; h in 512B LDS f16
// (dbuf, same-wave lgkmcnt ordering); XC prefetched 4 steps deep (named regs).
#define RSTEP2(XCREG, IDX, CURB)                                               \
    {                                                                          \
        float2 xc_use = XCREG;                                                 \
        if (i + 4 + (IDX) < 128) XCREG = *(const float2*)&XC[(i + 4 + (IDX)) * 128]; \
        const float4* hb = (const float4*)&h16[CURB][0];                       \
        float a0 = 0.f, a1 = 0.f, b0 = 0.f, b1 = 0.f;                          \
        _Pragma("unroll")                                                      \
        for (int q = 0; q < 16; q++) {                                         \
            union { float4 f4; h2_t h2[4]; } u;                                \
            u.f4 = hb[q];                                                      \
            a0 = FDOT2(u.h2[0], w2a[4 * q + 0], a0);                           \
            b0 = FDOT2(u.h2[0], w2b[4 * q + 0], b0);                           \
            a1 = FDOT2(u.h2[1], w2a[4 * q + 1], a1);                           \
            b1 = FDOT2(u.h2[1], w2b[4 * q + 1], b1);                           \
            a0 = FDOT2(u.h2[2], w2a[4 * q + 2], a0);                           \
            b0 = FDOT2(u.h2[2], w2b[4 * q + 2], b0);                           \
            a1 = FDOT2(u.h2[3], w2a[4 * q + 3], a1);                           \
            b1 = FDOT2(u.h2[3], w2b[4 * q + 3], b1);                           \
        }                                                                      \
        float v0 = xc_use.x + a0 + a1, v1 = xc_use.y + b0 + b1;                \
        v0 = 1.f / (1.f + __expf(-v0));                                        \
        v1 = 1.f / (1.f + __expf(-v1));                                        \
        h2_t hv; hv[0] = (_Float16)v0; hv[1] = (_Float16)v1;                   \
        h16[(CURB) ^ 1][lane] = hv;                                            \
        val = make_float2(v0, v1);                                             \
        *(float2*)&out[(size_t)(b * 128 + i + (IDX)) * 128 + c0] = val;        \
    }

__global__ __launch_bounds__(64) void k_recur(const float* __restrict__ hw,
                                              const float* __restrict__ wsf,
                                              float* __restrict__ out) {
    int b = blockIdx.x;
    __shared__ h2_t h16[2][64];         // [buf][64 half2] = 128 halves
    int lane = threadIdx.x;             // 0..63
    int c0 = 2 * lane;

    h2_t w2a[64], w2b[64];
    #pragma unroll
    for (int m = 0; m < 64; m++) {
        float2 e = *(const float2*)&hw[(2 * m) * 128 + c0];
        float2 o = *(const float2*)&hw[(2 * m + 1) * 128 + c0];
        h2_t p, q2;
        p[0] = (_Float16)e.x;  p[1] = (_Float16)o.x;
        q2[0] = (_Float16)e.y; q2[1] = (_Float16)o.y;
        w2a[m] = p; w2b[m] = q2;
    }
    h16[0][lane] = (h2_t)(_Float16)0.f;

    const float* XC = wsf + XC_OFF + (size_t)b * 128 * 128 + c0;
    float2 xc0 = *(const float2*)&XC[0 * 128];
    float2 xc1 = *(const float2*)&XC[1 * 128];
    float2 xc2 = *(const float2*)&XC[2 * 128];
    float2 xc3 = *(const float2*)&XC[3 * 128];
    float2 val = make_float2(0.f, 0.f);
    for (int i = 0; i < 128; i += 4) {
        RSTEP2(xc0, 0, 0)
        RSTEP2(xc1, 1, 1)
        RSTEP2(xc2, 2, 0)
        RSTEP2(xc3, 3, 1)
    }
    *(float2*)&out[(size_t)B_ * S_ * H_ + b * 128 + c0] = val;
}

extern "C" void kernel_launch(void* const* d_in, const int* in_sizes, int n_in,
                              void* d_out, int out_size, void* d_ws, size_t ws_size,
                              hipStream_t stream) {
    const float* x  = (const float*)d_in[0];
    const int*   tc = (const int*)d_in[1];
    const int*   dc = (const int*)d_in[2];
    const int*   mk = (const int*)d_in[3];   // bool masks pushed as int32
    const float* tw = (const float*)d_in[4];
    const float* dw = (const float*)d_in[5];
    const float* hw = (const float*)d_in[6];
    float*    out = (float*)d_out;
    float*    wsf = (float*)d_ws;
    unsigned* wsi = (unsigned*)d_ws;
    char*     wsb = (char*)d_ws;

    int useY = (ws_size >= NEED_BYTES) ? 1 : 0;
    if (!useY)  // fallback path accumulates into XC with atomics -> needs zeroed XC
        hipMemsetAsync(wsb, 0, (size_t)262144 * 4, stream);

    k_hist1<<<dim3(256), dim3(256), 0, stream>>>(tc, dc, mk, wsi);
    k_scan_all<<<dim3(1), dim3(1024), 0, stream>>>(wsi);
    k_scatter<<<dim3(256), dim3(256), 0, stream>>>(tc, dc, mk, wsi, useY);
    k_phaseA<<<dim3(NS, 16), dim3(256), 0, stream>>>(x, tw, wsi, wsf);
    k_phaseB<<<dim3(NS, 16), dim3(256), 0, stream>>>(dw, wsi, wsf, useY);
    if (useY) k_reduce<<<dim3(2048), dim3(128), 0, stream>>>(wsi, wsf);
    k_recur<<<dim3(16), dim3(64), 0, stream>>>(hw, wsf, out);
}

// Round 12
// 132.021 us; speedup vs baseline: 1.2636x; 1.2636x over previous
//
#include <hip/hip_runtime.h>
#include <math.h>

// STRNN: B=16, S=128, D=64, K=64, H=128, NSLOT+1=97 slots.
//
// Pipeline:
//  k_hist1    : per-block LDS histograms of t-slot / d-slot / per-(b,i) counts
//               (128 blocks x 2048 elems = 16 rows/block)
//  k_scan_all : exclusive scans -> per-(bin,block) bases + OFF_T/OFF_D/OFF_B
//  k_scatter  : one pass; LDS cursors; emits t-sorted entries, d-sorted refs, Y slots
//  k_phaseA   : per t-bucket GEMM  xt = x[b,j] @ Tw[t]  (VALU f32) -> XT f16 [tpos][64]
//  k_phaseB   : per d-bucket GEMM  y = xt @ Dw[d]  via MFMA f16 -> Y f16 [dstpos][128]
//  k_reduce   : XC[b,i,:] = f32 sum of its contiguous Y f16 rows
//  k_recur    : h = sigmoid(XC[b,i] + h@Wh); 2 waves/block, 1 col/lane, Wh in
//               VGPRs as half2, h in 512B LDS f16 dbuf, XC prefetched 4 deep.
//
// ws requirement: ~54 MB for the atomic-free path (guarded; fallback = atomicAdd XC).

#define B_ 16
#define S_ 128
#define D_ 64
#define K_ 64
#define H_ 128
#define NS 97
#define NB 128       // histogram blocks; 2048 elems (16 rows) each: NB*16 == 2048 rows
#define MAXE 132096  // B * S*(S+1)/2  (upper bound on valid triples)

// u32-index offsets into ws
#define XC_OFF 0                   // f32 [2048][128]
#define BH_T   262144              // u32 [97][128]
#define BH_D   (BH_T + NS * NB)    // u32 [97][128]
#define CNT_T  (BH_D + NS * NB)    // u32 [97]
#define CNT_D  (CNT_T + NS)        // u32 [97]
#define CNT_B  (CNT_D + NS)        // u32 [2048]
#define OFF_T  (CNT_B + 2048)      // u32 [98]
#define OFF_D  (OFF_T + 98)        // u32 [98]
#define OFF_B  (OFF_D + 98)        // u32 [2049]
#define ENT_T  291464              // u32 [MAXE]  (16B aligned)
#define ENT_DX (ENT_T + MAXE)      // u32 [MAXE] xt-row index (t-sorted pos)
#define ENT_DP (ENT_DX + MAXE)     // u32 [MAXE] Y-row (dst-sorted pos) [or dst in fallback]
#define XT16_OFF (ENT_DP + MAXE)   // f16 [MAXE][64]  (MAXE*32 u32)
#define Y16_OFF  (XT16_OFF + MAXE * 32)  // f16 [MAXE][128] (MAXE*64 u32)
#define NEED_BYTES ((size_t)(Y16_OFF + (size_t)MAXE * 64) * 4)

typedef _Float16 h2_t __attribute__((ext_vector_type(2)));
typedef _Float16 f16x8 __attribute__((ext_vector_type(8)));
typedef float f32x4 __attribute__((ext_vector_type(4)));

#if __has_builtin(__builtin_amdgcn_fdot2)
#define FDOT2(a, b, c) __builtin_amdgcn_fdot2((a), (b), (c), false)
#else
#define FDOT2(a, b, c) ((c) + (float)(a)[0] * (float)(b)[0] + (float)(a)[1] * (float)(b)[1])
#endif

// ---- binning: 128 blocks x 2048 elements (16 (b,i) rows per block) ----

__global__ __launch_bounds__(256) void k_hist1(const int* __restrict__ tc,
                                               const int* __restrict__ dc,
                                               const int* __restrict__ mk,
                                               unsigned* wsi) {
    __shared__ unsigned ht[NS], hd[NS], hb[16];
    int tid = threadIdx.x, blk = blockIdx.x;
    if (tid < NS) { ht[tid] = 0; hd[tid] = 0; }
    if (tid < 16) hb[tid] = 0;
    __syncthreads();
    int base = blk * 2048;
    #pragma unroll
    for (int u = 0; u < 8; u++) {
        int idx = base + tid + u * 256;
        int i = (idx >> 7) & 127, j = idx & 127;
        if (j <= i && mk[idx] != 0) {
            atomicAdd(&ht[tc[idx]], 1u);
            atomicAdd(&hd[dc[idx]], 1u);
            atomicAdd(&hb[(idx >> 7) & 15], 1u);
        }
    }
    __syncthreads();
    if (tid < NS) {
        wsi[BH_T + tid * NB + blk] = ht[tid];
        wsi[BH_D + tid * NB + blk] = hd[tid];
    }
    if (tid < 16) wsi[CNT_B + blk * 16 + tid] = hb[tid];
}

template <int CH>
__device__ unsigned scan_region(unsigned* in, unsigned* out, int L, unsigned* s) {
    int tid = threadIdx.x;
    unsigned loc[CH], sum = 0;
    #pragma unroll
    for (int k = 0; k < CH; k++) {
        int idx = tid * CH + k;
        loc[k] = (idx < L) ? in[idx] : 0u;
        sum += loc[k];
    }
    s[tid] = sum;
    __syncthreads();
    for (int o = 1; o < 1024; o <<= 1) {
        unsigned a = (tid >= o) ? s[tid - o] : 0u;
        __syncthreads();
        s[tid] += a;
        __syncthreads();
    }
    unsigned total = s[1023];
    unsigned run = s[tid] - sum;
    __syncthreads();
    #pragma unroll
    for (int k = 0; k < CH; k++) {
        int idx = tid * CH + k;
        if (idx < L) { out[idx] = run; run += loc[k]; }
    }
    __syncthreads();
    return total;
}

__global__ __launch_bounds__(1024) void k_scan_all(unsigned* wsi) {
    __shared__ unsigned s[1024];
    int tid = threadIdx.x;

    unsigned totT = scan_region<13>(wsi + BH_T, wsi + BH_T, NS * NB, s);
    if (tid < NS) {
        unsigned b0 = wsi[BH_T + tid * NB];
        unsigned b1 = (tid < NS - 1) ? wsi[BH_T + (tid + 1) * NB] : totT;
        wsi[OFF_T + tid] = b0;
        wsi[CNT_T + tid] = b1 - b0;
    }
    if (tid == 0) wsi[OFF_T + NS] = totT;
    __syncthreads();

    unsigned totD = scan_region<13>(wsi + BH_D, wsi + BH_D, NS * NB, s);
    if (tid < NS) {
        unsigned b0 = wsi[BH_D + tid * NB];
        unsigned b1 = (tid < NS - 1) ? wsi[BH_D + (tid + 1) * NB] : totD;
        wsi[OFF_D + tid] = b0;
        wsi[CNT_D + tid] = b1 - b0;
    }
    if (tid == 0) wsi[OFF_D + NS] = totD;
    __syncthreads();

    unsigned totB = scan_region<2>(wsi + CNT_B, wsi + OFF_B, 2048, s);
    if (tid == 0) wsi[OFF_B + 2048] = totB;
}

__global__ __launch_bounds__(256) void k_scatter(const int* __restrict__ tc,
                                                 const int* __restrict__ dc,
                                                 const int* __restrict__ mk,
                                                 unsigned* wsi, int useY) {
    __shared__ unsigned ct[NS], cd[NS], cb[16];
    int tid = threadIdx.x, blk = blockIdx.x;
    if (tid < NS) {
        ct[tid] = wsi[BH_T + tid * NB + blk];
        cd[tid] = wsi[BH_D + tid * NB + blk];
    }
    if (tid < 16) cb[tid] = wsi[OFF_B + blk * 16 + tid];
    __syncthreads();
    int base = blk * 2048;
    #pragma unroll
    for (int u = 0; u < 8; u++) {
        int idx = base + tid + u * 256;
        int i = (idx >> 7) & 127, j = idx & 127, b = idx >> 14;
        if (j <= i && mk[idx] != 0) {
            unsigned t = (unsigned)tc[idx], d = (unsigned)dc[idx];
            unsigned tpos = atomicAdd(&ct[t], 1u);
            wsi[ENT_T + tpos] = (unsigned)b | ((unsigned)i << 4) | ((unsigned)j << 11)
                              | (t << 18) | (d << 25);
            unsigned dpos = atomicAdd(&cd[d], 1u);
            unsigned yp = useY ? atomicAdd(&cb[(idx >> 7) & 15], 1u) : (unsigned)(idx >> 7);
            wsi[ENT_DX + dpos] = tpos;
            wsi[ENT_DP + dpos] = yp;
        }
    }
}

// phase A: xt[entry][kk] = sum_dd x[b,j][dd] * Tw[t][dd][kk]; store XT as f16
__global__ __launch_bounds__(256) void k_phaseA(const float* __restrict__ x,
                                                const float* __restrict__ tw,
                                                unsigned* wsi, float* wsf) {
    int t = blockIdx.x, c = blockIdx.y;
    int rows = (int)wsi[CNT_T + t] - c * 128;
    if (rows <= 0) return;
    if (rows > 128) rows = 128;
    unsigned base = wsi[OFF_T + t] + c * 128;

    __shared__ float stw[4096];     // Tw[t] row-major [dd][kk]
    __shared__ float sx[8192];      // x rows, XOR-swizzled in 4-float units
    __shared__ unsigned ent[128];
    int tid = threadIdx.x;

    const float4* twg = (const float4*)(tw + t * 4096);
    float4* stw4 = (float4*)stw;
    #pragma unroll
    for (int q = 0; q < 4; q++) stw4[q * 256 + tid] = twg[q * 256 + tid];
    if (tid < 128) ent[tid] = (tid < rows) ? wsi[ENT_T + base + tid] : 0u;
    __syncthreads();

    int lane16 = tid & 15, rquot = tid >> 4;
    #pragma unroll
    for (int p = 0; p < 8; p++) {
        int r = p * 16 + rquot;
        float4 v = make_float4(0.f, 0.f, 0.f, 0.f);
        if (r < rows) {
            unsigned e = ent[r];
            int b = e & 15, j = (e >> 11) & 127;
            v = *(const float4*)(x + (b * S_ + j) * D_ + lane16 * 4);
        }
        int col4 = lane16 ^ (r & 15);
        float* dst = &sx[r * 64 + col4 * 4];
        dst[0] = v.x; dst[1] = v.y; dst[2] = v.z; dst[3] = v.w;
    }
    __syncthreads();

    int rgrp = tid & 15, cgrp = tid >> 4;   // 8 rows (rgrp+16i) x 4 cols (cgrp*4..)
    float4 acc[8];
    #pragma unroll
    for (int i = 0; i < 8; i++) acc[i] = make_float4(0.f, 0.f, 0.f, 0.f);
    #pragma unroll 4
    for (int dd = 0; dd < 64; dd++) {
        float4 w = stw4[dd * 16 + cgrp];
        int s_idx = (((dd >> 2) ^ rgrp) << 2) + (dd & 3);
        #pragma unroll
        for (int i = 0; i < 8; i++) {
            float a = sx[(rgrp + 16 * i) * 64 + s_idx];
            acc[i].x += a * w.x; acc[i].y += a * w.y;
            acc[i].z += a * w.z; acc[i].w += a * w.w;
        }
    }
    _Float16* XT = (_Float16*)(wsf + XT16_OFF);
    #pragma unroll
    for (int i = 0; i < 8; i++) {
        int r = rgrp + 16 * i;
        if (r < rows) {
            union { _Float16 h[4]; double d64; } u;
            u.h[0] = (_Float16)acc[i].x; u.h[1] = (_Float16)acc[i].y;
            u.h[2] = (_Float16)acc[i].z; u.h[3] = (_Float16)acc[i].w;
            *(double*)&XT[(size_t)(base + r) * 64 + cgrp * 4] = u.d64;
        }
    }
}

// phase B (MFMA f16): y[rows x 128] = XT16-rows[rows x 64] @ Dw[d][64 x 128] -> Y f16.
__global__ __launch_bounds__(256) void k_phaseB(const float* __restrict__ dw,
                                                unsigned* wsi, float* wsf, int useY) {
    int d = blockIdx.x, c = blockIdx.y;
    int rows = (int)wsi[CNT_D + d] - c * 128;
    if (rows <= 0) return;
    if (rows > 128) rows = 128;
    unsigned base = wsi[OFF_D + d] + c * 128;

    __shared__ _Float16 sa[128 * 64];     // A: XT rows f16, chunk-swizzled (16 KB)
    __shared__ _Float16 sb[64 * 128];     // B: Dw f16 [k][h] linear (16 KB)
    __shared__ unsigned entx_s[128], entp_s[128];
    int tid = threadIdx.x;

    if (tid < 128) {
        entx_s[tid] = (tid < rows) ? wsi[ENT_DX + base + tid] : 0u;
        entp_s[tid] = (tid < rows) ? wsi[ENT_DP + base + tid] : 0u;
    }
    // stage Dw -> f16 linear (element order preserved)
    const float4* dwg = (const float4*)(dw + (size_t)d * 8192);
    #pragma unroll
    for (int q = 0; q < 8; q++) {
        float4 v = dwg[q * 256 + tid];
        union { _Float16 h[4]; double d64; } u;
        u.h[0] = (_Float16)v.x; u.h[1] = (_Float16)v.y;
        u.h[2] = (_Float16)v.z; u.h[3] = (_Float16)v.w;
        *(double*)&sb[(q * 256 + tid) * 4] = u.d64;
    }
    __syncthreads();   // entx_s ready for XT staging

    // stage XT16 rows: thread = (row r = tid>>1, k-half hh = tid&1); pure copy
    {
        int r = tid >> 1, hh = tid & 1;
        const _Float16* XT = (const _Float16*)(wsf + XT16_OFF);
        const f16x8* src = (const f16x8*)(XT + (size_t)entx_s[r] * 64 + hh * 32);
        #pragma unroll
        for (int mm = 0; mm < 4; mm++) {
            f16x8 hv = {0, 0, 0, 0, 0, 0, 0, 0};
            if (r < rows) hv = src[mm];
            int chunk = hh * 4 + mm;                       // 8-half chunk 0..7
            *(f16x8*)&sa[r * 64 + (chunk ^ (r & 7)) * 8] = hv;
        }
    }
    __syncthreads();

    int w = tid >> 6, lane = tid & 63;
    int l15 = lane & 15, lg = lane >> 4;                   // lg = k-group
    f16x8 bf[2][2];
    #pragma unroll
    for (int n = 0; n < 2; n++) {
        int col = w * 32 + n * 16 + l15;
        #pragma unroll
        for (int ks = 0; ks < 2; ks++) {
            int kb = ks * 32 + lg * 8;
            f16x8 t;
            #pragma unroll
            for (int e = 0; e < 8; e++) t[e] = sb[(kb + e) * 128 + col];
            bf[n][ks] = t;
        }
    }
    f32x4 acc[8][2];
    f32x4 z = {0.f, 0.f, 0.f, 0.f};
    #pragma unroll
    for (int m = 0; m < 8; m++) { acc[m][0] = z; acc[m][1] = z; }

    #pragma unroll
    for (int m = 0; m < 8; m++) {
        int row = m * 16 + l15;
        f16x8 a0 = *(f16x8*)&sa[row * 64 + ((lg) ^ (row & 7)) * 8];        // ks=0
        f16x8 a1 = *(f16x8*)&sa[row * 64 + ((4 + lg) ^ (row & 7)) * 8];    // ks=1
        #pragma unroll
        for (int n = 0; n < 2; n++) {
            acc[m][n] = __builtin_amdgcn_mfma_f32_16x16x32_f16(a0, bf[n][0], acc[m][n], 0, 0, 0);
            acc[m][n] = __builtin_amdgcn_mfma_f32_16x16x32_f16(a1, bf[n][1], acc[m][n], 0, 0, 0);
        }
    }

    // epilogue: C layout col = lane&15, row = (lane>>4)*4 + reg  [m89-verified]
    if (useY) {
        _Float16* Y16 = (_Float16*)(wsf + Y16_OFF);
        #pragma unroll
        for (int m = 0; m < 8; m++) {
            #pragma unroll
            for (int reg = 0; reg < 4; reg++) {
                int row = m * 16 + lg * 4 + reg;
                if (row < rows) {
                    _Float16* p = Y16 + (size_t)entp_s[row] * 128 + w * 32 + l15;
                    p[0]  = (_Float16)acc[m][0][reg];
                    p[16] = (_Float16)acc[m][1][reg];
                }
            }
        }
    } else {
        float* XC = wsf + XC_OFF;
        #pragma unroll
        for (int m = 0; m < 8; m++) {
            #pragma unroll
            for (int reg = 0; reg < 4; reg++) {
                int row = m * 16 + lg * 4 + reg;
                if (row < rows) {
                    float* p = XC + (size_t)entp_s[row] * 128 + w * 32 + l15;
                    atomicAdd(p + 0,  acc[m][0][reg]);
                    atomicAdd(p + 16, acc[m][1][reg]);
                }
            }
        }
    }
}

// XC[b,i,:] = f32 sum of this (b,i)'s contiguous Y16 rows
__global__ __launch_bounds__(128) void k_reduce(unsigned* wsi, float* wsf) {
    int bi = blockIdx.x, tid = threadIdx.x;
    unsigned n = wsi[CNT_B + bi], off = wsi[OFF_B + bi];
    const _Float16* Yp = (const _Float16*)(wsf + Y16_OFF) + (size_t)off * 128 + tid;
    float a0 = 0.f, a1 = 0.f, a2 = 0.f, a3 = 0.f;
    unsigned e = 0;
    for (; e + 4 <= n; e += 4) {
        a0 += (float)Yp[(size_t)e * 128];
        a1 += (float)Yp[(size_t)(e + 1) * 128];
        a2 += (float)Yp[(size_t)(e + 2) * 128];
        a3 += (float)Yp[(size_t)(e + 3) * 128];
    }
    for (; e < n; e++) a0 += (float)Yp[(size_t)e * 128];
    wsf[XC_OFF + (size_t)bi * 128 + tid] = (a0 + a1) + (a2 + a3);
}

// recurrence (r9 best): one block (128 thr = 2 waves) per b; lane owns col =
// wv*64+lane; Wh column in 64 half2 VGPRs; h in 512B LDS f16 dbuf; XC prefetched
// FOUR steps ahead into named registers; one barrier per step.
#define RSTEP(XCREG, IDX, CURB)                                                \
    {                                                                          \
        float xc_use = XCREG;                                                  \
        if (i + 4 + (IDX) < 128) XCREG = XC[(i + 4 + (IDX)) * 128];            \
        const float4* hb = (const float4*)&h16[CURB][0];                       \
        float a0 = 0.f, a1 = 0.f, a2 = 0.f, a3 = 0.f;                          \
        _Pragma("unroll")                                                      \
        for (int q = 0; q < 16; q++) {                                         \
            union { float4 f4; h2_t h2[4]; } u;                                \
            u.f4 = hb[q];                                                      \
            a0 = FDOT2(u.h2[0], w2[4 * q + 0], a0);                            \
            a1 = FDOT2(u.h2[1], w2[4 * q + 1], a1);                            \
            a2 = FDOT2(u.h2[2], w2[4 * q + 2], a2);                            \
            a3 = FDOT2(u.h2[3], w2[4 * q + 3], a3);                            \
        }                                                                      \
        float v = xc_use + (a0 + a1) + (a2 + a3);                              \
        v = 1.f / (1.f + __expf(-v));                                          \
        val = v;                                                               \
        ((_Float16*)&h16[(CURB) ^ 1][0])[col] = (_Float16)v;                   \
        out[(size_t)(b * 128 + i + (IDX)) * 128 + col] = v;                    \
        __syncthreads();                                                       \
    }

__global__ __launch_bounds__(128) void k_recur(const float* __restrict__ hw,
                                               const float* __restrict__ wsf,
                                               float* __restrict__ out) {
    int b = blockIdx.x;
    __shared__ h2_t h16[2][64];         // [buf][64 half2] = 128 halves
    int tid = threadIdx.x;
    int lane = tid & 63, wv = tid >> 6;
    int col = wv * 64 + lane;

    h2_t w2[64];
    #pragma unroll
    for (int m = 0; m < 64; m++) {
        h2_t p;
        p[0] = (_Float16)hw[(2 * m) * 128 + col];       // coalesced across lanes
        p[1] = (_Float16)hw[(2 * m + 1) * 128 + col];
        w2[m] = p;
    }
    if (tid < 64) h16[0][tid] = (h2_t)(_Float16)0.f;
    __syncthreads();

    const float* XC = wsf + XC_OFF + (size_t)b * 128 * 128 + col;
    float xc0 = XC[0 * 128], xc1 = XC[1 * 128], xc2 = XC[2 * 128], xc3 = XC[3 * 128];
    float val = 0.f;
    for (int i = 0; i < 128; i += 4) {
        RSTEP(xc0, 0, 0)
        RSTEP(xc1, 1, 1)
        RSTEP(xc2, 2, 0)
        RSTEP(xc3, 3, 1)
    }
    out[(size_t)B_ * S_ * H_ + b * 128 + col] = val;
}

extern "C" void kernel_launch(void* const* d_in, const int* in_sizes, int n_in,
                              void* d_out, int out_size, void* d_ws, size_t ws_size,
                              hipStream_t stream) {
    const float* x  = (const float*)d_in[0];
    const int*   tc = (const int*)d_in[1];
    const int*   dc = (const int*)d_in[2];
    const int*   mk = (const int*)d_in[3];   // bool masks pushed as int32
    const float* tw = (const float*)d_in[4];
    const float* dw = (const float*)d_in[5];
    const float* hw = (const float*)d_in[6];
    float*    out = (float*)d_out;
    float*    wsf = (float*)d_ws;
    unsigned* wsi = (unsigned*)d_ws;
    char*     wsb = (char*)d_ws;

    int useY = (ws_size >= NEED_BYTES) ? 1 : 0;
    if (!useY)  // fallback path accumulates into XC with atomics -> needs zeroed XC
        hipMemsetAsync(wsb, 0, (size_t)262144 * 4, stream);

    k_hist1<<<dim3(NB), dim3(256), 0, stream>>>(tc, dc, mk, wsi);
    k_scan_all<<<dim3(1), dim3(1024), 0, stream>>>(wsi);
    k_scatter<<<dim3(NB), dim3(256), 0, stream>>>(tc, dc, mk, wsi, useY);
    k_phaseA<<<dim3(NS, 16), dim3(256), 0, stream>>>(x, tw, wsi, wsf);
    k_phaseB<<<dim3(NS, 16), dim3(256), 0, stream>>>(dw, wsi, wsf, useY);
    if (useY) k_reduce<<<dim3(2048), dim3(128), 0, stream>>>(wsi, wsf);
    k_recur<<<dim3(16), dim3(128), 0, stream>>>(hw, wsf, out);
}